// Round 1
// baseline (520.721 us; speedup 1.0000x reference)
//
#include <hip/hip_runtime.h>

typedef unsigned short u16;
typedef unsigned int u32;
typedef short bf16x8 __attribute__((ext_vector_type(8)));
typedef float f32x4 __attribute__((ext_vector_type(4)));

#define B_ 4
#define S_ 2048
#define E_ 1024
#define H_ 16
#define FF_ 4096
#define M_ 8192  // B*S

__device__ __forceinline__ u16 f2bf(float f) {
    u32 u = __float_as_uint(f);
    u32 r = (u + 0x7FFFu + ((u >> 16) & 1u)) >> 16;
    return (u16)r;
}
__device__ __forceinline__ float bf2f(u16 v) {
    return __uint_as_float(((u32)v) << 16);
}

__device__ __forceinline__ void gload16(const void* g, void* l) {
    __builtin_amdgcn_global_load_lds(
        (__attribute__((address_space(1))) void*)g,
        (__attribute__((address_space(3))) void*)l, 16, 0, 0);
}

// ---------------- fp32 -> bf16 cast (weights) ----------------
__global__ __launch_bounds__(256) void cvt_kernel(const float* __restrict__ in,
                                                  u16* __restrict__ out, int n4) {
    int i = blockIdx.x * 256 + threadIdx.x;
    if (i < n4) {
        float4 v = ((const float4*)in)[i];
        ushort4 o;
        o.x = f2bf(v.x); o.y = f2bf(v.y); o.z = f2bf(v.z); o.w = f2bf(v.w);
        ((ushort4*)out)[i] = o;
    }
}

// ---------------- LayerNorm (fp32 in -> bf16 out), one row per block ----------------
__global__ __launch_bounds__(256) void ln_kernel(const float* __restrict__ x,
                                                 const float* __restrict__ g,
                                                 const float* __restrict__ bb,
                                                 u16* __restrict__ out) {
    int row = blockIdx.x;
    int t = threadIdx.x;
    const float4* xr = (const float4*)(x + (size_t)row * E_);
    float4 v = xr[t];
    float s = v.x + v.y + v.z + v.w;
    float sq = v.x * v.x + v.y * v.y + v.z * v.z + v.w * v.w;
    for (int o = 1; o < 64; o <<= 1) {
        s += __shfl_xor(s, o, 64);
        sq += __shfl_xor(sq, o, 64);
    }
    __shared__ float ss[4], sqs[4];
    int w = t >> 6, l = t & 63;
    if (l == 0) { ss[w] = s; sqs[w] = sq; }
    __syncthreads();
    s = ss[0] + ss[1] + ss[2] + ss[3];
    sq = sqs[0] + sqs[1] + sqs[2] + sqs[3];
    float mean = s * (1.0f / E_);
    float var = sq * (1.0f / E_) - mean * mean;
    float rstd = rsqrtf(var + 1e-5f);
    float4 gv = ((const float4*)g)[t];
    float4 bv = ((const float4*)bb)[t];
    ushort4 o4;
    o4.x = f2bf((v.x - mean) * rstd * gv.x + bv.x);
    o4.y = f2bf((v.y - mean) * rstd * gv.y + bv.y);
    o4.z = f2bf((v.z - mean) * rstd * gv.z + bv.z);
    o4.w = f2bf((v.w - mean) * rstd * gv.w + bv.w);
    ((ushort4*)(out + (size_t)row * E_))[t] = o4;
}

// ---------------- GEMM: C[M,N] = A[M,K] (bf16) @ Bt[N,K]^T (bf16) + bias ----------------
// m97 structure: 128x128 tile, BK=32, 4 waves, global_load_lds(16B), 16x16x32 MFMA.
// EPI: 0 = bf16 store; 1 = fp32 store with residual add; 2 = GELU -> bf16 store
template <int EPI>
__global__ __launch_bounds__(256) void gemm_bt(const u16* __restrict__ A,
                                               const u16* __restrict__ Bt,
                                               const float* __restrict__ bias,
                                               void* __restrict__ outp,
                                               const float* __restrict__ resid,
                                               int N, int K) {
    __shared__ u16 As[128 * 32];
    __shared__ u16 Bs[128 * 32];
    int t = threadIdx.x;
    int wv = t >> 6, l = t & 63, c = l & 15, gq = l >> 4;
    int wr = wv >> 1, wc = wv & 1;
    int m0 = blockIdx.y * 128, n0 = blockIdx.x * 128;

    f32x4 acc[4][4];
    f32x4 zf = {0.f, 0.f, 0.f, 0.f};
#pragma unroll
    for (int i = 0; i < 4; i++)
#pragma unroll
        for (int j = 0; j < 4; j++) acc[i][j] = zf;

    const size_t Kb = (size_t)K * 2;
    int o = 16 * t;
    int arow = o >> 6, acolb = o & 63;
    const char* aptr = (const char*)A + (size_t)(m0 + arow) * Kb + acolb;
    const char* bptr = (const char*)Bt + (size_t)(n0 + arow) * Kb + acolb;
    int K32 = K >> 5;

    for (int kt = 0; kt < K32; ++kt) {
        __syncthreads();
        gload16(aptr, (char*)As + o);
        gload16(aptr + 64 * Kb, (char*)As + o + 4096);
        gload16(bptr, (char*)Bs + o);
        gload16(bptr + 64 * Kb, (char*)Bs + o + 4096);
        aptr += 64;
        bptr += 64;
        __syncthreads();
        bf16x8 af[4], bfg[4];
#pragma unroll
        for (int mi = 0; mi < 4; mi++)
            af[mi] = *(const bf16x8*)((const char*)As + (((wr * 64 + mi * 16 + c) << 6) | (gq << 4)));
#pragma unroll
        for (int ni = 0; ni < 4; ni++)
            bfg[ni] = *(const bf16x8*)((const char*)Bs + (((wc * 64 + ni * 16 + c) << 6) | (gq << 4)));
#pragma unroll
        for (int mi = 0; mi < 4; mi++)
#pragma unroll
            for (int ni = 0; ni < 4; ni++)
                acc[mi][ni] = __builtin_amdgcn_mfma_f32_16x16x32_bf16(af[mi], bfg[ni], acc[mi][ni], 0, 0, 0);
    }

    float bias_v[4];
#pragma unroll
    for (int ni = 0; ni < 4; ni++) bias_v[ni] = bias[n0 + wc * 64 + ni * 16 + c];

#pragma unroll
    for (int mi = 0; mi < 4; mi++)
#pragma unroll
        for (int ni = 0; ni < 4; ni++)
#pragma unroll
            for (int j = 0; j < 4; j++) {
                int row = m0 + wr * 64 + mi * 16 + gq * 4 + j;
                int col = n0 + wc * 64 + ni * 16 + c;
                float v = acc[mi][ni][j] + bias_v[ni];
                size_t idx = (size_t)row * N + col;
                if (EPI == 2) v = 0.5f * v * (1.0f + erff(v * 0.70710678118f));
                if (EPI == 1)
                    ((float*)outp)[idx] = resid[idx] + v;
                else
                    ((u16*)outp)[idx] = f2bf(v);
            }
}

// ---------------- Flash attention with custom mask ----------------
// Grid: (B*H, S/128). 4 waves; each wave owns 32 Q rows. KVBLK = 64.
// qkv layout: [B*S, 3E] bf16; q at +0, k at +E, v at +2E, head offset h*64.
// Mask: col > row  ||  (col % 32) == 31  -> -inf.
__global__ __launch_bounds__(256) void attn_kernel(const u16* __restrict__ qkv,
                                                   u16* __restrict__ aout) {
    __shared__ u16 Ks[64 * 64];
    __shared__ u16 Vt[64 * 64];
    __shared__ u16 Ps[4][32 * 64];
    int t = threadIdx.x, wv = t >> 6, l = t & 63, c = l & 15, gq = l >> 4;
    int bh = blockIdx.x, qt = blockIdx.y;
    int b = bh >> 4, h = bh & 15;
    int i0 = qt * 128;

    // Q fragments in registers, pre-scaled by 1/sqrt(64)
    bf16x8 qf[2][2];
#pragma unroll
    for (int mf = 0; mf < 2; mf++)
#pragma unroll
        for (int ks = 0; ks < 2; ks++) {
            const u16* src = qkv + (size_t)(b * S_ + i0 + 32 * wv + 16 * mf + c) * 3072 + h * 64 + 32 * ks + 8 * gq;
            uint4 d16 = *(const uint4*)src;
            u32 uu[4] = {d16.x, d16.y, d16.z, d16.w};
#pragma unroll
            for (int e = 0; e < 8; e++) {
                u16 raw = (e & 1) ? (u16)(uu[e >> 1] >> 16) : (u16)(uu[e >> 1] & 0xffffu);
                qf[mf][ks][e] = (short)f2bf(bf2f(raw) * 0.125f);
            }
        }

    f32x4 O[2][4];
    f32x4 zf = {0.f, 0.f, 0.f, 0.f};
    float mrun[2][4], lrun[2][4];
#pragma unroll
    for (int a = 0; a < 2; a++)
#pragma unroll
        for (int j = 0; j < 4; j++) {
            mrun[a][j] = -INFINITY;
            lrun[a][j] = 0.f;
#pragma unroll
            for (int nd = 0; nd < 4; nd++) O[a][nd] = zf;
        }

    int ntiles = 2 * qt + 2;
    for (int jt = 0; jt < ntiles; ++jt) {
        int j0 = jt * 64;
        __syncthreads();
        // stage K tile [64 rows x 64 d], XOR-swizzled rows
#pragma unroll
        for (int p = 0; p < 2; p++) {
            int oo = 16 * t + 4096 * p;
            int row = oo >> 7, colb = oo & 127;
            const u16* src = qkv + E_ + (size_t)(b * S_ + j0 + row) * 3072 + h * 64 + (colb >> 1);
            uint4 d16 = *(const uint4*)src;
            int el = (((row << 6) + (colb >> 1)) ^ ((row & 7) << 3));
            *(uint4*)&Ks[el] = d16;
        }
        // stage V transposed: Vt[d][j], XOR-swizzled; conflict-free writes (row = lane)
#pragma unroll
        for (int p = 0; p < 2; p++) {
            int db = wv + 4 * p;
            const u16* src = qkv + 2 * E_ + (size_t)(b * S_ + j0 + l) * 3072 + h * 64 + db * 8;
            uint4 d16 = *(const uint4*)src;
            u32 uu[4] = {d16.x, d16.y, d16.z, d16.w};
#pragma unroll
            for (int e = 0; e < 8; e++) {
                u16 raw = (e & 1) ? (u16)(uu[e >> 1] >> 16) : (u16)(uu[e >> 1] & 0xffffu);
                int d = db * 8 + e;
                Vt[((d << 6) + l) ^ ((d & 7) << 3)] = raw;
            }
        }
        __syncthreads();

        // QK^T: S[32 x 64] per wave
        bf16x8 kfr[4][2];
#pragma unroll
        for (int nf = 0; nf < 4; nf++)
#pragma unroll
            for (int ks = 0; ks < 2; ks++) {
                int kr = 16 * nf + c;
                kfr[nf][ks] = *(const bf16x8*)&Ks[((kr << 6) + 32 * ks + 8 * gq) ^ ((kr & 7) << 3)];
            }
        f32x4 sf[2][4];
#pragma unroll
        for (int mf = 0; mf < 2; mf++)
#pragma unroll
            for (int nf = 0; nf < 4; nf++) {
                sf[mf][nf] = zf;
#pragma unroll
                for (int ks = 0; ks < 2; ks++)
                    sf[mf][nf] = __builtin_amdgcn_mfma_f32_16x16x32_bf16(qf[mf][ks], kfr[nf][ks], sf[mf][nf], 0, 0, 0);
            }

        // mask + online softmax
#pragma unroll
        for (int mf = 0; mf < 2; mf++)
#pragma unroll
            for (int j = 0; j < 4; j++) {
                int row = i0 + 32 * wv + 16 * mf + 4 * gq + j;
                float mx = -INFINITY;
#pragma unroll
                for (int nf = 0; nf < 4; nf++) {
                    int col = j0 + 16 * nf + c;
                    float v = sf[mf][nf][j];
                    bool bad = (col > row) || ((col & 31) == 31);
                    v = bad ? -INFINITY : v;
                    sf[mf][nf][j] = v;
                    mx = fmaxf(mx, v);
                }
                mx = fmaxf(mx, __shfl_xor(mx, 1, 64));
                mx = fmaxf(mx, __shfl_xor(mx, 2, 64));
                mx = fmaxf(mx, __shfl_xor(mx, 4, 64));
                mx = fmaxf(mx, __shfl_xor(mx, 8, 64));
                float mold = mrun[mf][j];
                float mnew = fmaxf(mold, mx);
                float sc = __expf(mold - mnew);  // 0 on first tile (mold=-inf)
                mrun[mf][j] = mnew;
                float psum = 0.f;
#pragma unroll
                for (int nf = 0; nf < 4; nf++) {
                    float p = __expf(sf[mf][nf][j] - mnew);
                    sf[mf][nf][j] = p;
                    psum += p;
                }
                psum += __shfl_xor(psum, 1, 64);
                psum += __shfl_xor(psum, 2, 64);
                psum += __shfl_xor(psum, 4, 64);
                psum += __shfl_xor(psum, 8, 64);
                lrun[mf][j] = lrun[mf][j] * sc + psum;
#pragma unroll
                for (int nd = 0; nd < 4; nd++) O[mf][nd][j] *= sc;
            }

        // P -> wave-private swizzled LDS (bf16)
#pragma unroll
        for (int mf = 0; mf < 2; mf++)
#pragma unroll
            for (int nf = 0; nf < 4; nf++)
#pragma unroll
                for (int j = 0; j < 4; j++) {
                    int pr = 16 * mf + 4 * gq + j;
                    Ps[wv][((pr << 6) + 16 * nf + c) ^ ((pr & 7) << 3)] = f2bf(sf[mf][nf][j]);
                }
        asm volatile("s_waitcnt lgkmcnt(0)" ::: "memory");
        __builtin_amdgcn_sched_barrier(0);

        // PV: O += P @ V
        bf16x8 pf[2][2], vfr[2][4];
#pragma unroll
        for (int ma = 0; ma < 2; ma++)
#pragma unroll
            for (int ks = 0; ks < 2; ks++) {
                int pr = 16 * ma + c;
                pf[ma][ks] = *(const bf16x8*)&Ps[wv][((pr << 6) + 32 * ks + 8 * gq) ^ ((pr & 7) << 3)];
            }
#pragma unroll
        for (int ks = 0; ks < 2; ks++)
#pragma unroll
            for (int nd = 0; nd < 4; nd++) {
                int d = 16 * nd + c;
                vfr[ks][nd] = *(const bf16x8*)&Vt[((d << 6) + 32 * ks + 8 * gq) ^ ((d & 7) << 3)];
            }
#pragma unroll
        for (int ma = 0; ma < 2; ma++)
#pragma unroll
            for (int nd = 0; nd < 4; nd++)
#pragma unroll
                for (int ks = 0; ks < 2; ks++)
                    O[ma][nd] = __builtin_amdgcn_mfma_f32_16x16x32_bf16(pf[ma][ks], vfr[ks][nd], O[ma][nd], 0, 0, 0);
    }

    // write attn output in [B*S, E] layout (bf16)
#pragma unroll
    for (int ma = 0; ma < 2; ma++)
#pragma unroll
        for (int j = 0; j < 4; j++) {
            float inv = 1.0f / lrun[ma][j];
            int row = i0 + 32 * wv + 16 * ma + 4 * gq + j;
#pragma unroll
            for (int nd = 0; nd < 4; nd++) {
                int d = 16 * nd + c;
                aout[(size_t)(b * S_ + row) * E_ + h * 64 + d] = f2bf(O[ma][nd][j] * inv);
            }
        }
}

extern "C" void kernel_launch(void* const* d_in, const int* in_sizes, int n_in,
                              void* d_out, int out_size, void* d_ws, size_t ws_size,
                              hipStream_t stream) {
    const float* x = (const float*)d_in[0];
    const float* ln1_g = (const float*)d_in[2];
    const float* ln1_b = (const float*)d_in[3];
    const float* ln2_g = (const float*)d_in[4];
    const float* ln2_b = (const float*)d_in[5];
    const float* w_qkv = (const float*)d_in[6];
    const float* b_qkv = (const float*)d_in[7];
    const float* w_o = (const float*)d_in[8];
    const float* b_o = (const float*)d_in[9];
    const float* w_fc1 = (const float*)d_in[10];
    const float* b_fc1 = (const float*)d_in[11];
    const float* w_fc2 = (const float*)d_in[12];
    const float* b_fc2 = (const float*)d_in[13];
    float* out = (float*)d_out;
    char* ws = (char*)d_ws;

    // workspace layout (bytes); regions reused once dead
    u16* wqkv_bf = (u16*)(ws);                  // 6291456
    u16* wo_bf   = (u16*)(ws + 6291456);        // 2097152
    u16* wfc1_bf = (u16*)(ws + 8388608);        // 8388608
    u16* wfc2_bf = (u16*)(ws + 16777216);       // 8388608
    u16* xn_bf   = (u16*)(ws + 25165824);       // 16777216 (LN1 out; reused as LN2 out)
    u16* qkv_bf  = (u16*)(ws + 41943040);       // 50331648 (reused by ffn1)
    u16* ffn1_bf = (u16*)(ws + 41943040);       // 67108864
    u16* attn_bf = (u16*)(ws + 92274688);       // 16777216
    float* x2    = (float*)(ws + 109051904);    // 33554432
    (void)in_sizes; (void)n_in; (void)out_size; (void)ws_size;

    cvt_kernel<<<3072, 256, 0, stream>>>(w_qkv, wqkv_bf, 786432);
    cvt_kernel<<<1024, 256, 0, stream>>>(w_o, wo_bf, 262144);
    cvt_kernel<<<4096, 256, 0, stream>>>(w_fc1, wfc1_bf, 1048576);
    cvt_kernel<<<4096, 256, 0, stream>>>(w_fc2, wfc2_bf, 1048576);

    ln_kernel<<<M_, 256, 0, stream>>>(x, ln1_g, ln1_b, xn_bf);

    gemm_bt<0><<<dim3(24, 64), 256, 0, stream>>>(xn_bf, wqkv_bf, b_qkv, qkv_bf, nullptr, 3072, 1024);

    attn_kernel<<<dim3(64, 16), 256, 0, stream>>>(qkv_bf, attn_bf);

    gemm_bt<1><<<dim3(8, 64), 256, 0, stream>>>(attn_bf, wo_bf, b_o, x2, x, 1024, 1024);

    ln_kernel<<<M_, 256, 0, stream>>>(x2, ln2_g, ln2_b, xn_bf);

    gemm_bt<2><<<dim3(32, 64), 256, 0, stream>>>(xn_bf, wfc1_bf, b_fc1, ffn1_bf, nullptr, 4096, 1024);

    gemm_bt<1><<<dim3(8, 64), 256, 0, stream>>>(ffn1_bf, wfc2_bf, b_fc2, out, x2, 1024, 4096);
}